// Round 2
// baseline (591.494 us; speedup 1.0000x reference)
//
#include <hip/hip_runtime.h>
#include <math.h>

#define DD 128
#define KK 8
#define LN_EPS 1e-5f
#define NORM_EPS 1e-12f

// ---------------------------------------------------------------------------
// Kernel 1 (tiny, 1 block): precompute per-j coefficient table + scalars into
// d_ws so the main kernel can read them with wave-uniform SCALAR loads.
// ws layout (floats): [0,2048): coef[j*16 + {wg0..7, g^2, g*beta, bias, pad}]
//                     [2048,2080): pk[8], q0k[8], cg2s, cgbs, cb2s
// ---------------------------------------------------------------------------
__global__ void l1q_prep(const float* __restrict__ b, const float* __restrict__ gamma,
                         const float* __restrict__ beta, const float* __restrict__ cb,
                         float* __restrict__ ws)
{
    __shared__ float invn_s[KK];
    const int t = threadIdx.x;  // 128 threads
    if (t < KK) {
        float s = 0.f;
        for (int j = 0; j < DD; ++j) { float v = cb[t * DD + j]; s = fmaf(v, v, s); }
        invn_s[t] = 1.0f / fmaxf(sqrtf(s), NORM_EPS);
    }
    __syncthreads();
    {
        float g = gamma[t], be = beta[t];
        float* cj = ws + t * 16;
        #pragma unroll
        for (int k = 0; k < KK; ++k) cj[k] = cb[k * DD + t] * invn_s[k] * g;
        cj[8] = g * g; cj[9] = g * be; cj[10] = b[t];
        cj[11] = cj[12] = cj[13] = cj[14] = cj[15] = 0.f;
    }
    float* scal = ws + DD * 16;
    if (t < KK) {
        float p = 0.f, q = 0.f, in = invn_s[t];
        for (int j = 0; j < DD; ++j) {
            p = fmaf(cb[t * DD + j] * in, gamma[j], p);
            q = fmaf(cb[t * DD + j] * in, beta[j], q);
        }
        scal[t] = p;       // pk
        scal[8 + t] = q;   // q0k
    }
    if (t == 16) { float s = 0.f; for (int j = 0; j < DD; ++j) { float g = gamma[j]; s = fmaf(g, g, s); } scal[16] = s; }
    if (t == 17) { float s = 0.f; for (int j = 0; j < DD; ++j) s = fmaf(gamma[j], beta[j], s); scal[17] = s; }
    if (t == 18) { float s = 0.f; for (int j = 0; j < DD; ++j) { float v = beta[j]; s = fmaf(v, v, s); } scal[18] = s; }
}

// ---------------------------------------------------------------------------
// Main kernel: row-per-thread. x row in VGPRs; W and coef read with
// wave-uniform indices straight from global -> compiler emits s_load into
// SGPRs -> v_fma with SGPR broadcast operand. No bulk LDS traffic.
// ---------------------------------------------------------------------------
__global__ __launch_bounds__(256, 3)
void l1q_main(const float* __restrict__ x, const float* __restrict__ W,
              const float* __restrict__ cb, const float* __restrict__ coef,
              const float* __restrict__ scal,
              float* __restrict__ out_idx, float* __restrict__ out_soft,
              float* __restrict__ out_emb, float* __restrict__ out_log,
              int B)
{
    __shared__ int bestl[256];
    const int t = threadIdx.x;
    const int row = blockIdx.x * 256 + t;
    const int lrow = row < B ? row : 0;   // B is a multiple of 256; guard anyway

    // ---- x row -> VGPRs (issued first to hide latency) ----
    float xr[DD];
    {
        const float4* xp = (const float4*)(x + (size_t)lrow * DD);
        #pragma unroll
        for (int i = 0; i < DD / 4; ++i) {
            float4 v = xp[i];
            xr[4 * i + 0] = v.x; xr[4 * i + 1] = v.y;
            xr[4 * i + 2] = v.z; xr[4 * i + 3] = v.w;
        }
    }

    // ---- streamed matvec: h_j never stored; 13 accumulators capture all
    //      downstream functionals of h ----
    float s1 = 0.f, s2 = 0.f, t1 = 0.f, t2 = 0.f, r1 = 0.f;
    float u[KK];
    #pragma unroll
    for (int k = 0; k < KK; ++k) u[k] = 0.f;

    #pragma unroll 2
    for (int j = 0; j < DD; ++j) {
        const float* wj = W + j * DD;        // wave-uniform -> scalar loads
        float a0 = 0.f, a1 = 0.f, a2 = 0.f, a3 = 0.f;
        #pragma unroll
        for (int i = 0; i < DD; i += 4) {
            a0 = fmaf(xr[i + 0], wj[i + 0], a0);
            a1 = fmaf(xr[i + 1], wj[i + 1], a1);
            a2 = fmaf(xr[i + 2], wj[i + 2], a2);
            a3 = fmaf(xr[i + 3], wj[i + 3], a3);
        }
        const float* cj = coef + j * 16;     // wave-uniform -> scalar loads
        float c8 = cj[8], c9 = cj[9], c10 = cj[10];
        float h = ((a0 + a1) + (a2 + a3)) + c10;
        s1 += h;
        s2 = fmaf(h, h, s2);
        t2 = fmaf(c8, h * h, t2);
        t1 = fmaf(c8, h, t1);
        r1 = fmaf(c9, h, r1);
        u[0] = fmaf(cj[0], h, u[0]); u[1] = fmaf(cj[1], h, u[1]);
        u[2] = fmaf(cj[2], h, u[2]); u[3] = fmaf(cj[3], h, u[3]);
        u[4] = fmaf(cj[4], h, u[4]); u[5] = fmaf(cj[5], h, u[5]);
        u[6] = fmaf(cj[6], h, u[6]); u[7] = fmaf(cj[7], h, u[7]);
    }

    // ---- epilogue ----
    const float invD = 1.0f / (float)DD;
    float mu = s1 * invD;
    float var = fmaf(-mu, mu, s2 * invD);
    float istd = 1.0f / sqrtf(var + LN_EPS);
    float cg2s = scal[16], cgbs = scal[17], cb2s = scal[18];  // scalar loads
    float nrm2 = istd * istd * (t2 - 2.f * mu * t1 + mu * mu * cg2s)
               + 2.f * istd * (r1 - mu * cgbs) + cb2s;
    float rinv = 1.0f / fmaxf(sqrtf(fmaxf(nrm2, 0.f)), NORM_EPS);

    float lg[KK];
    #pragma unroll
    for (int k = 0; k < KK; ++k)
        lg[k] = (istd * (u[k] - mu * scal[k]) + scal[8 + k]) * rinv;  // TEMP=1

    float mx = lg[0]; int bi = 0;
    #pragma unroll
    for (int k = 1; k < KK; ++k) if (lg[k] > mx) { mx = lg[k]; bi = k; }

    float ex[KK], se = 0.f;
    #pragma unroll
    for (int k = 0; k < KK; ++k) { ex[k] = expf(lg[k] - mx); se += ex[k]; }
    float rse = 1.0f / se;

    if (row < B) {
        out_idx[row] = (float)bi;
        float4* os = (float4*)(out_soft + (size_t)row * KK);
        os[0] = make_float4(ex[0] * rse, ex[1] * rse, ex[2] * rse, ex[3] * rse);
        os[1] = make_float4(ex[4] * rse, ex[5] * rse, ex[6] * rse, ex[7] * rse);
        float4* ol = (float4*)(out_log + (size_t)row * KK);
        ol[0] = make_float4(lg[0], lg[1], lg[2], lg[3]);
        ol[1] = make_float4(lg[4], lg[5], lg[6], lg[7]);
    }
    bestl[t] = bi;
    __syncthreads();

    // ---- cooperative coalesced embedding write: emb[row] = codebook[best[row]] ----
    {
        const size_t base4 = (size_t)blockIdx.x * 256 * (DD / 4);
        float4* eo = (float4*)out_emb;
        const float4* cb4 = (const float4*)cb;
        #pragma unroll
        for (int i = 0; i < 32; ++i) {
            int e4 = t + i * 256;
            int r  = e4 >> 5;              // 32 float4 per row
            int d4 = e4 & 31;
            int rr = blockIdx.x * 256 + r;
            if (rr < B) eo[base4 + e4] = cb4[bestl[r] * 32 + d4];
        }
    }
}

extern "C" void kernel_launch(void* const* d_in, const int* in_sizes, int n_in,
                              void* d_out, int out_size, void* d_ws, size_t ws_size,
                              hipStream_t stream) {
    const float* x     = (const float*)d_in[0];
    const float* W     = (const float*)d_in[1];
    const float* b     = (const float*)d_in[2];
    const float* gamma = (const float*)d_in[3];
    const float* beta  = (const float*)d_in[4];
    const float* cb    = (const float*)d_in[5];
    const int B = in_sizes[0] / DD;

    float* ws   = (float*)d_ws;           // needs 2080 floats
    float* coef = ws;
    float* scal = ws + DD * 16;

    float* out    = (float*)d_out;
    float* o_idx  = out;                              // (B,)
    float* o_soft = out + (size_t)B;                  // (B,K)
    float* o_emb  = out + (size_t)B * (1 + KK);       // (B,D)
    float* o_log  = out + (size_t)B * (1 + KK + DD);  // (B,K)

    hipLaunchKernelGGL(l1q_prep, dim3(1), dim3(DD), 0, stream, b, gamma, beta, cb, ws);
    const int grid = (B + 255) / 256;
    hipLaunchKernelGGL(l1q_main, dim3(grid), dim3(256), 0, stream,
                       x, W, cb, coef, scal, o_idx, o_soft, o_emb, o_log, B);
}

// Round 3
// 351.661 us; speedup vs baseline: 1.6820x; 1.6820x over previous
//
#include <hip/hip_runtime.h>
#include <math.h>

#define DD 128
#define KK 8
#define LN_EPS 1e-5f
#define NORM_EPS 1e-12f

typedef __attribute__((ext_vector_type(8))) short bf16x8;
typedef __attribute__((ext_vector_type(4))) float f32x4;
typedef unsigned int uint;
typedef unsigned short ushort;

// ws layout (bytes):
//   [0, 110592)        wsA: packed bf16 A-frags of W_ext:
//                      [split(3)][jt(9)][ks(4)][lane(64)][8 bf16]
//   [110592, 111616)   g2b: 128 x {gamma^2, bias} float2
//   [111616, 111744)   scal[32]: 0..7 pk, 8..15 q0k, 16 cg2s, 17 cgbs,
//                      18 cb2s, 19 cs1, 20 ct1, 21 cr1, 22..29 cuk
#define WSA_USHORTS (3 * 9 * 4 * 64 * 8)
#define G2B_OFF_F   (110592 / 4)
#define SCAL_OFF_F  (111616 / 4)

// exact 3-way bf16 split: x ~= h + m + l (each a bf16 value in high 16 bits)
__device__ inline void split3(float x, uint& h, uint& m, uint& l) {
    uint u0 = __float_as_uint(x);
    uint rh = (u0 + 0x7FFFu + ((u0 >> 16) & 1u)) & 0xFFFF0000u;
    float xh = __uint_as_float(rh);
    float r1 = x - xh;                       // exact
    uint u1 = __float_as_uint(r1);
    uint rm = (u1 + 0x7FFFu + ((u1 >> 16) & 1u)) & 0xFFFF0000u;
    float xm = __uint_as_float(rm);
    float r2 = r1 - xm;                      // exact
    uint u2 = __float_as_uint(r2);
    uint rl = (u2 + 0x7FFFu + ((u2 >> 16) & 1u));
    h = rh; m = rm; l = rl;
}

__device__ inline void split2pack(float e0, float e1, uint& ph, uint& pm, uint& pl) {
    uint h0, m0, l0, h1, m1, l1;
    split3(e0, h0, m0, l0);
    split3(e1, h1, m1, l1);
    ph = (h0 >> 16) | (h1 & 0xFFFF0000u);
    pm = (m0 >> 16) | (m1 & 0xFFFF0000u);
    pl = (l0 >> 16) | (l1 & 0xFFFF0000u);
}

union FragU { uint4 u; bf16x8 f; };
union AccU  { f32x4 v; float a[4]; };

// ---------------------------------------------------------------------------
// prep0: scalar tables (1 block x 128 threads)
// ---------------------------------------------------------------------------
__global__ void l1q_prep0(const float* __restrict__ b, const float* __restrict__ gamma,
                          const float* __restrict__ beta, const float* __restrict__ cb,
                          float* __restrict__ ws)
{
    __shared__ float invn_s[KK];
    const int t = threadIdx.x;  // 128
    if (t < KK) {
        float s = 0.f;
        for (int j = 0; j < DD; ++j) { float v = cb[t * DD + j]; s = fmaf(v, v, s); }
        invn_s[t] = 1.0f / fmaxf(sqrtf(s), NORM_EPS);
    }
    __syncthreads();
    // g2b table
    {
        float g = gamma[t];
        float* g2b = ws + G2B_OFF_F;
        g2b[2 * t]     = g * g;
        g2b[2 * t + 1] = b[t];
    }
    float* scal = ws + SCAL_OFF_F;
    if (t < KK) {
        float in = invn_s[t];
        float p = 0.f, q = 0.f, cu = 0.f;
        for (int j = 0; j < DD; ++j) {
            float c = cb[t * DD + j] * in;
            p  = fmaf(c, gamma[j], p);
            q  = fmaf(c, beta[j], q);
            cu = fmaf(c * gamma[j], b[j], cu);
        }
        scal[t]      = p;   // pk
        scal[8 + t]  = q;   // q0k
        scal[22 + t] = cu;  // cuk
    }
    if (t == 16) { float s = 0.f; for (int j = 0; j < DD; ++j) { float g = gamma[j]; s = fmaf(g, g, s); } scal[16] = s; }
    if (t == 17) { float s = 0.f; for (int j = 0; j < DD; ++j) s = fmaf(gamma[j], beta[j], s); scal[17] = s; }
    if (t == 18) { float s = 0.f; for (int j = 0; j < DD; ++j) { float v = beta[j]; s = fmaf(v, v, s); } scal[18] = s; }
    if (t == 19) { float s = 0.f; for (int j = 0; j < DD; ++j) s += b[j]; scal[19] = s; }                        // cs1
    if (t == 20) { float s = 0.f; for (int j = 0; j < DD; ++j) s = fmaf(gamma[j] * gamma[j], b[j], s); scal[20] = s; } // ct1
    if (t == 21) { float s = 0.f; for (int j = 0; j < DD; ++j) s = fmaf(gamma[j] * beta[j], b[j], s); scal[21] = s; }  // cr1
}

// ---------------------------------------------------------------------------
// prepA: build W_ext (144x128: W rows + 11 folded linear-functional rows),
// 3-way split to bf16, pack into MFMA A-fragment layout in ws.
// grid 36 blocks: bid -> (jt, ks). 256 threads.
// ---------------------------------------------------------------------------
__global__ void l1q_prepA(const float* __restrict__ W, const float* __restrict__ b,
                          const float* __restrict__ gamma, const float* __restrict__ beta,
                          const float* __restrict__ cb, ushort* __restrict__ wsA)
{
    __shared__ float invn_s[KK];
    __shared__ float we[11][DD];    // fold weights w_e[j]
    __shared__ float wext[16][32];  // this block's fp32 tile
    const int t = threadIdx.x;
    const int jt = blockIdx.x >> 2;   // 0..8
    const int ks = blockIdx.x & 3;    // 0..3

    if (jt == 8) {
        if (t < KK) {
            float s = 0.f;
            for (int j = 0; j < DD; ++j) { float v = cb[t * DD + j]; s = fmaf(v, v, s); }
            invn_s[t] = 1.0f / fmaxf(sqrtf(s), NORM_EPS);
        }
        __syncthreads();
        for (int idx = t; idx < 11 * DD; idx += 256) {
            int e = idx / DD, j = idx % DD;
            float g = gamma[j];
            float v;
            if (e == 0)      v = 1.0f;
            else if (e == 1) v = g * g;
            else if (e == 2) v = g * beta[j];
            else             v = cb[(e - 3) * DD + j] * invn_s[e - 3] * g;
            we[e][j] = v;
        }
        __syncthreads();
    }

    // fill wext[jl][kk] for j_ext = jt*16+jl, k = ks*32+kk
    for (int idx = t; idx < 512; idx += 256) {
        int jl = idx >> 5, kk = idx & 31;
        int k = ks * 32 + kk;
        float val;
        if (jt < 8) {
            val = W[(jt * 16 + jl) * DD + k];
        } else if (jl < 11) {
            float s = 0.f;
            for (int j = 0; j < DD; ++j) s = fmaf(we[jl][j], W[j * DD + k], s);
            val = s;
        } else {
            val = 0.f;
        }
        wext[jl][kk] = val;
    }
    __syncthreads();

    // pack: element (jl, kk) -> split s, dst ((s*9+jt)*4+ks)*512 + lane*8 + i
    for (int idx = t; idx < 512; idx += 256) {
        int jl = idx >> 5, kk = idx & 31;
        int quad = kk >> 3, i = kk & 7;
        int lane = quad * 16 + jl;
        uint h, m, l;
        split3(wext[jl][kk], h, m, l);
        int base = jt * 4 + ks;
        wsA[(0 * 36 + base) * 512 + lane * 8 + i] = (ushort)(h >> 16);
        wsA[(1 * 36 + base) * 512 + lane * 8 + i] = (ushort)(m >> 16);
        wsA[(2 * 36 + base) * 512 + lane * 8 + i] = (ushort)(l >> 16);
    }
}

// ---------------------------------------------------------------------------
// main: 256 threads = 4 waves, 64 rows/wave. D[j_ext][m] = W_ext x x^T via
// 6-way split-bf16 MFMA 16x16x32. Lane holds col m = lane&15 (+16*set),
// rows j = quad*4+reg (+16*jt). Folded sums land in jt==8.
// ---------------------------------------------------------------------------
__global__ __launch_bounds__(256, 2)
void l1q_main(const float* __restrict__ x, const ushort* __restrict__ wsA,
              const float* __restrict__ wsf, const float* __restrict__ cb,
              float* __restrict__ out_idx, float* __restrict__ out_soft,
              float* __restrict__ out_emb, float* __restrict__ out_log,
              int B)
{
    __shared__ float g2b_s[256];
    __shared__ float scal_s[32];
    __shared__ float gath[4][320];   // [wave][16 m x 20]
    __shared__ int   besti[4][64];   // [wave][s*16+ml]

    const int t = threadIdx.x;
    const int wave = t >> 6;
    const int lane = t & 63;
    const int ml = lane & 15;
    const int q  = lane >> 4;
    const int rowbase = blockIdx.x * 256 + wave * 64;

    g2b_s[t] = wsf[G2B_OFF_F + t];
    if (t < 32) scal_s[t] = wsf[SCAL_OFF_F + t];
    __syncthreads();

    f32x4 acc[4][9];
    #pragma unroll
    for (int s = 0; s < 4; ++s)
        #pragma unroll
        for (int jt = 0; jt < 9; ++jt)
            acc[s][jt] = (f32x4){0.f, 0.f, 0.f, 0.f};

    for (int ks = 0; ks < 4; ++ks) {
        // x fragments for 4 row-subsets, 3 splits each
        FragU xh[4], xm[4], xl[4];
        #pragma unroll
        for (int s = 0; s < 4; ++s) {
            const float* xp = x + (size_t)(rowbase + s * 16 + ml) * DD + ks * 32 + q * 8;
            float4 a = *(const float4*)xp;
            float4 c = *(const float4*)(xp + 4);
            split2pack(a.x, a.y, xh[s].u.x, xm[s].u.x, xl[s].u.x);
            split2pack(a.z, a.w, xh[s].u.y, xm[s].u.y, xl[s].u.y);
            split2pack(c.x, c.y, xh[s].u.z, xm[s].u.z, xl[s].u.z);
            split2pack(c.z, c.w, xh[s].u.w, xm[s].u.w, xl[s].u.w);
        }
        #pragma unroll
        for (int jt = 0; jt < 9; ++jt) {
            const int base = (jt * 4 + ks) * 512 + lane * 8;
            FragU wh, wm, wl;
            wh.u = *(const uint4*)(wsA + 0 * 36 * 512 + base);
            wm.u = *(const uint4*)(wsA + 1 * 36 * 512 + base);
            wl.u = *(const uint4*)(wsA + 2 * 36 * 512 + base);
            #pragma unroll
            for (int s = 0; s < 4; ++s) {
                f32x4 c = acc[s][jt];
                c = __builtin_amdgcn_mfma_f32_16x16x32_bf16(wl.f, xh[s].f, c, 0, 0, 0);
                c = __builtin_amdgcn_mfma_f32_16x16x32_bf16(wh.f, xl[s].f, c, 0, 0, 0);
                c = __builtin_amdgcn_mfma_f32_16x16x32_bf16(wm.f, xm[s].f, c, 0, 0, 0);
                c = __builtin_amdgcn_mfma_f32_16x16x32_bf16(wm.f, xh[s].f, c, 0, 0, 0);
                c = __builtin_amdgcn_mfma_f32_16x16x32_bf16(wh.f, xm[s].f, c, 0, 0, 0);
                c = __builtin_amdgcn_mfma_f32_16x16x32_bf16(wh.f, xh[s].f, c, 0, 0, 0);
                acc[s][jt] = c;
            }
        }
    }

    // ---- quadratic epilogue: s2 = sum h^2, t2 = sum g^2 h^2 ----
    float s2a[4] = {0.f, 0.f, 0.f, 0.f};
    float t2a[4] = {0.f, 0.f, 0.f, 0.f};
    #pragma unroll
    for (int jt = 0; jt < 8; ++jt) {
        #pragma unroll
        for (int r = 0; r < 4; ++r) {
            int j = jt * 16 + q * 4 + r;
            float2 gb = *(const float2*)&g2b_s[2 * j];
            #pragma unroll
            for (int s = 0; s < 4; ++s) {
                AccU a; a.v = acc[s][jt];
                float h = a.a[r] + gb.y;
                float h2 = h * h;
                s2a[s] += h2;
                t2a[s] = fmaf(gb.x, h2, t2a[s]);
            }
        }
    }
    #pragma unroll
    for (int s = 0; s < 4; ++s) {
        s2a[s] += __shfl_xor(s2a[s], 16);
        s2a[s] += __shfl_xor(s2a[s], 32);
        t2a[s] += __shfl_xor(t2a[s], 16);
        t2a[s] += __shfl_xor(t2a[s], 32);
    }

    const float inv128 = 1.0f / 128.0f;
    const float cg2s = scal_s[16], cgbs = scal_s[17], cb2s = scal_s[18];
    const float cs1 = scal_s[19], ct1 = scal_s[20], cr1 = scal_s[21];

    #pragma unroll
    for (int s = 0; s < 4; ++s) {
        // all-gather the 11 folded linear sums (jt==8 accs) across quads via LDS
        AccU mine; mine.v = acc[s][8];
        *(float4*)&gath[wave][ml * 20 + q * 4] = *(float4*)mine.a;
        __builtin_amdgcn_s_waitcnt(0);  // lgkmcnt(0); wave-internal ordering
        float4 A = *(const float4*)&gath[wave][ml * 20 + 0];
        float4 Bv = *(const float4*)&gath[wave][ml * 20 + 4];
        float4 C = *(const float4*)&gath[wave][ml * 20 + 8];

        float s1  = A.x + cs1;
        float t1  = A.y + ct1;
        float r1v = A.z + cr1;
        float u[KK] = {A.w + scal_s[22], Bv.x + scal_s[23], Bv.y + scal_s[24],
                       Bv.z + scal_s[25], Bv.w + scal_s[26], C.x + scal_s[27],
                       C.y + scal_s[28], C.z + scal_s[29]};

        float mu = s1 * inv128;
        float var = fmaf(-mu, mu, s2a[s] * inv128);
        float istd = 1.0f / sqrtf(var + LN_EPS);
        float nrm2 = istd * istd * (t2a[s] - 2.f * mu * t1 + mu * mu * cg2s)
                   + 2.f * istd * (r1v - mu * cgbs) + cb2s;
        float rinv = 1.0f / fmaxf(sqrtf(fmaxf(nrm2, 0.f)), NORM_EPS);

        float lg[KK];
        #pragma unroll
        for (int k = 0; k < KK; ++k)
            lg[k] = (istd * (u[k] - mu * scal_s[k]) + scal_s[8 + k]) * rinv;

        float mx = lg[0]; int bi = 0;
        #pragma unroll
        for (int k = 1; k < KK; ++k) if (lg[k] > mx) { mx = lg[k]; bi = k; }

        float ex[KK], se = 0.f;
        #pragma unroll
        for (int k = 0; k < KK; ++k) { ex[k] = expf(lg[k] - mx); se += ex[k]; }
        float rse = 1.0f / se;

        const int m = rowbase + s * 16 + ml;
        if (q == 0) {
            out_idx[m] = (float)bi;
            *(float4*)&out_log[(size_t)m * KK + 4] = make_float4(lg[4], lg[5], lg[6], lg[7]);
            besti[wave][s * 16 + ml] = bi;
        } else if (q == 1) {
            *(float4*)&out_soft[(size_t)m * KK] = make_float4(ex[0] * rse, ex[1] * rse, ex[2] * rse, ex[3] * rse);
        } else if (q == 2) {
            *(float4*)&out_soft[(size_t)m * KK + 4] = make_float4(ex[4] * rse, ex[5] * rse, ex[6] * rse, ex[7] * rse);
        } else {
            *(float4*)&out_log[(size_t)m * KK] = make_float4(lg[0], lg[1], lg[2], lg[3]);
        }
    }

    // ---- embedding: emb[row] = codebook[best[row]], coalesced ----
    __builtin_amdgcn_s_waitcnt(0);
    const float4* cb4 = (const float4*)cb;
    float4* eo = (float4*)out_emb;
    #pragma unroll
    for (int s = 0; s < 4; ++s) {
        #pragma unroll
        for (int i = 0; i < 4; ++i) {
            int f4 = lane + 64 * i;          // 0..255 over 16 rows x 16... (16*32=512/2)
            int rl = f4 >> 5;                // row-local 0..7
            int c  = f4 & 31;
            int k0 = besti[wave][s * 16 + rl];
            eo[(size_t)(rowbase + s * 16 + rl) * 32 + c] = cb4[k0 * 32 + c];
            int rl2 = (f4 + 256) >> 5;       // rows 8..15
            int k1 = besti[wave][s * 16 + rl2];
            eo[(size_t)(rowbase + s * 16 + rl2) * 32 + c] = cb4[k1 * 32 + c];
        }
    }
}

extern "C" void kernel_launch(void* const* d_in, const int* in_sizes, int n_in,
                              void* d_out, int out_size, void* d_ws, size_t ws_size,
                              hipStream_t stream) {
    const float* x     = (const float*)d_in[0];
    const float* W     = (const float*)d_in[1];
    const float* b     = (const float*)d_in[2];
    const float* gamma = (const float*)d_in[3];
    const float* beta  = (const float*)d_in[4];
    const float* cb    = (const float*)d_in[5];
    const int B = in_sizes[0] / DD;

    float*  ws  = (float*)d_ws;
    ushort* wsA = (ushort*)d_ws;

    float* out    = (float*)d_out;
    float* o_idx  = out;
    float* o_soft = out + (size_t)B;
    float* o_emb  = out + (size_t)B * (1 + KK);
    float* o_log  = out + (size_t)B * (1 + KK + DD);

    hipLaunchKernelGGL(l1q_prep0, dim3(1), dim3(128), 0, stream, b, gamma, beta, cb, ws);
    hipLaunchKernelGGL(l1q_prepA, dim3(36), dim3(256), 0, stream, W, b, gamma, beta, cb, wsA);
    const int grid = B / 256;
    hipLaunchKernelGGL(l1q_main, dim3(grid), dim3(256), 0, stream,
                       x, wsA, ws, cb, o_idx, o_soft, o_emb, o_log, B);
}

// Round 4
// 325.596 us; speedup vs baseline: 1.8166x; 1.0801x over previous
//
#include <hip/hip_runtime.h>
#include <math.h>

#define DD 128
#define KK 8
#define LN_EPS 1e-5f
#define NORM_EPS 1e-12f

typedef __attribute__((ext_vector_type(8))) short bf16x8;
typedef __attribute__((ext_vector_type(4))) float f32x4;
typedef unsigned int uint;
typedef unsigned short ushort;

// ws layout (bytes):
//   [0, 110592)        wsA: packed bf16 A-frags of W_ext:
//                      [split(3)][jt(9)][ks(4)][lane(64)][8 bf16]
//   [110592, 111616)   g2b: 128 x {gamma^2, bias} float2
//   [111616, 111744)   scal[32]: 0..7 pk, 8..15 q0k, 16 cg2s, 17 cgbs,
//                      18 cb2s, 19 cs1, 20 ct1, 21 cr1, 22..29 cuk
#define G2B_OFF_F   (110592 / 4)
#define SCAL_OFF_F  (111616 / 4)

// exact 3-way bf16 split with RNE (used in prep only)
__device__ inline void split3(float x, uint& h, uint& m, uint& l) {
    uint u0 = __float_as_uint(x);
    uint rh = (u0 + 0x7FFFu + ((u0 >> 16) & 1u)) & 0xFFFF0000u;
    float xh = __uint_as_float(rh);
    float r1 = x - xh;                       // exact
    uint u1 = __float_as_uint(r1);
    uint rm = (u1 + 0x7FFFu + ((u1 >> 16) & 1u)) & 0xFFFF0000u;
    float xm = __uint_as_float(rm);
    float r2 = r1 - xm;                      // exact
    uint u2 = __float_as_uint(r2);
    uint rl = (u2 + 0x7FFFu + ((u2 >> 16) & 1u));
    h = rh; m = rm; l = rl;
}

// cheap truncating 3-way split for the main loop. Residuals r1, r2 are exact
// regardless of rounding mode; only the last limb is truncated (err ~2^-24 rel).
__device__ inline void split3t(float x, uint& h, uint& m, uint& l) {
    uint u0 = __float_as_uint(x);
    float xh = __uint_as_float(u0 & 0xFFFF0000u);
    float r1 = x - xh;
    uint u1 = __float_as_uint(r1);
    float xm = __uint_as_float(u1 & 0xFFFF0000u);
    float r2 = r1 - xm;
    h = u0; m = u1; l = __float_as_uint(r2);
}

// pack high halves of two split words: dst = (a0>>16) | (a1 & 0xFFFF0000)
__device__ inline uint packhi(uint a1, uint a0) {
    return __builtin_amdgcn_perm(a1, a0, 0x07060302u);
}

__device__ inline void split2packt(float e0, float e1, uint& ph, uint& pm, uint& pl) {
    uint h0, m0, l0, h1, m1, l1;
    split3t(e0, h0, m0, l0);
    split3t(e1, h1, m1, l1);
    ph = packhi(h1, h0);
    pm = packhi(m1, m0);
    pl = packhi(l1, l0);
}

union FragU { uint4 u; bf16x8 f; };
union AccU  { f32x4 v; float a[4]; };

// ---------------------------------------------------------------------------
// prep0: scalar tables (1 block x 128 threads)
// ---------------------------------------------------------------------------
__global__ void l1q_prep0(const float* __restrict__ b, const float* __restrict__ gamma,
                          const float* __restrict__ beta, const float* __restrict__ cb,
                          float* __restrict__ ws)
{
    __shared__ float invn_s[KK];
    const int t = threadIdx.x;  // 128
    if (t < KK) {
        float s = 0.f;
        for (int j = 0; j < DD; ++j) { float v = cb[t * DD + j]; s = fmaf(v, v, s); }
        invn_s[t] = 1.0f / fmaxf(sqrtf(s), NORM_EPS);
    }
    __syncthreads();
    {
        float g = gamma[t];
        float* g2b = ws + G2B_OFF_F;
        g2b[2 * t]     = g * g;
        g2b[2 * t + 1] = b[t];
    }
    float* scal = ws + SCAL_OFF_F;
    if (t < KK) {
        float in = invn_s[t];
        float p = 0.f, q = 0.f, cu = 0.f;
        for (int j = 0; j < DD; ++j) {
            float c = cb[t * DD + j] * in;
            p  = fmaf(c, gamma[j], p);
            q  = fmaf(c, beta[j], q);
            cu = fmaf(c * gamma[j], b[j], cu);
        }
        scal[t]      = p;   // pk
        scal[8 + t]  = q;   // q0k
        scal[22 + t] = cu;  // cuk
    }
    if (t == 16) { float s = 0.f; for (int j = 0; j < DD; ++j) { float g = gamma[j]; s = fmaf(g, g, s); } scal[16] = s; }
    if (t == 17) { float s = 0.f; for (int j = 0; j < DD; ++j) s = fmaf(gamma[j], beta[j], s); scal[17] = s; }
    if (t == 18) { float s = 0.f; for (int j = 0; j < DD; ++j) { float v = beta[j]; s = fmaf(v, v, s); } scal[18] = s; }
    if (t == 19) { float s = 0.f; for (int j = 0; j < DD; ++j) s += b[j]; scal[19] = s; }                        // cs1
    if (t == 20) { float s = 0.f; for (int j = 0; j < DD; ++j) s = fmaf(gamma[j] * gamma[j], b[j], s); scal[20] = s; } // ct1
    if (t == 21) { float s = 0.f; for (int j = 0; j < DD; ++j) s = fmaf(gamma[j] * beta[j], b[j], s); scal[21] = s; }  // cr1
}

// ---------------------------------------------------------------------------
// prepA: build W_ext (144x128: W rows + 11 folded linear-functional rows),
// 3-way split to bf16, pack into MFMA A-fragment layout in ws.
// grid 36 blocks: bid -> (jt, ks). 256 threads. (verified layout, round 3)
// ---------------------------------------------------------------------------
__global__ void l1q_prepA(const float* __restrict__ W, const float* __restrict__ b,
                          const float* __restrict__ gamma, const float* __restrict__ beta,
                          const float* __restrict__ cb, ushort* __restrict__ wsA)
{
    __shared__ float invn_s[KK];
    __shared__ float we[11][DD];
    __shared__ float wext[16][32];
    const int t = threadIdx.x;
    const int jt = blockIdx.x >> 2;   // 0..8
    const int ks = blockIdx.x & 3;    // 0..3

    if (jt == 8) {
        if (t < KK) {
            float s = 0.f;
            for (int j = 0; j < DD; ++j) { float v = cb[t * DD + j]; s = fmaf(v, v, s); }
            invn_s[t] = 1.0f / fmaxf(sqrtf(s), NORM_EPS);
        }
        __syncthreads();
        for (int idx = t; idx < 11 * DD; idx += 256) {
            int e = idx / DD, j = idx % DD;
            float g = gamma[j];
            float v;
            if (e == 0)      v = 1.0f;
            else if (e == 1) v = g * g;
            else if (e == 2) v = g * beta[j];
            else             v = cb[(e - 3) * DD + j] * invn_s[e - 3] * g;
            we[e][j] = v;
        }
        __syncthreads();
    }

    for (int idx = t; idx < 512; idx += 256) {
        int jl = idx >> 5, kk = idx & 31;
        int k = ks * 32 + kk;
        float val;
        if (jt < 8) {
            val = W[(jt * 16 + jl) * DD + k];
        } else if (jl < 11) {
            float s = 0.f;
            for (int j = 0; j < DD; ++j) s = fmaf(we[jl][j], W[j * DD + k], s);
            val = s;
        } else {
            val = 0.f;
        }
        wext[jl][kk] = val;
    }
    __syncthreads();

    for (int idx = t; idx < 512; idx += 256) {
        int jl = idx >> 5, kk = idx & 31;
        int quad = kk >> 3, i = kk & 7;
        int lane = quad * 16 + jl;
        uint h, m, l;
        split3(wext[jl][kk], h, m, l);
        int base = jt * 4 + ks;
        wsA[(0 * 36 + base) * 512 + lane * 8 + i] = (ushort)(h >> 16);
        wsA[(1 * 36 + base) * 512 + lane * 8 + i] = (ushort)(m >> 16);
        wsA[(2 * 36 + base) * 512 + lane * 8 + i] = (ushort)(l >> 16);
    }
}

// ---------------------------------------------------------------------------
// main: 1024 threads = 16 waves, 16 rows/wave, 256 rows/block. Whole packed
// W_ext (110592 B) staged into LDS once; x prefetched one ks ahead into regs.
// acc[jt] lane(q,ml): row j_ext = jt*16 + q*4 + reg, col m = ml.
// ---------------------------------------------------------------------------
__global__ __launch_bounds__(1024, 4)
void l1q_main(const float* __restrict__ x, const ushort* __restrict__ wsA,
              const float* __restrict__ wsf, const float* __restrict__ cb,
              float* __restrict__ out_idx, float* __restrict__ out_soft,
              float* __restrict__ out_emb, float* __restrict__ out_log,
              int B)
{
    __shared__ uint4 Wl4[6912];        // 110592 B: packed W_ext frags
    __shared__ float gath[16][320];    // folded-sum all-gather, per wave
    __shared__ int   besti[16][16];
    __shared__ float g2b_s[256];
    __shared__ float scal_s[32];

    const int t = threadIdx.x;
    const int wave = t >> 6;
    const int lane = t & 63;
    const int ml = lane & 15;
    const int q  = lane >> 4;
    const int rowbase = blockIdx.x * 256 + wave * 16;
    const int row = rowbase + ml;

    // x row pointer; issue ks=0 loads early (overlap with staging)
    const float* xp = x + (size_t)row * DD + q * 8;
    float4 ra = *(const float4*)(xp + 0);
    float4 rc = *(const float4*)(xp + 4);

    // stage packed W into LDS (each thread <=7 uint4 from L2)
    {
        const uint4* src = (const uint4*)wsA;
        #pragma unroll
        for (int i = 0; i < 7; ++i) {
            int idx = t + i * 1024;
            if (idx < 6912) Wl4[idx] = src[idx];
        }
    }
    if (t < 256) g2b_s[t] = wsf[G2B_OFF_F + t];
    if (t < 32)  scal_s[t] = wsf[SCAL_OFF_F + t];
    __syncthreads();

    f32x4 acc[9];
    #pragma unroll
    for (int jt = 0; jt < 9; ++jt) acc[jt] = (f32x4){0.f, 0.f, 0.f, 0.f};

    #pragma unroll
    for (int ks = 0; ks < 4; ++ks) {
        // prefetch next ks (redundant reload at ks=3, L1-hit)
        int kn = ks < 3 ? ks + 1 : 3;
        float4 na = *(const float4*)(xp + kn * 32 + 0);
        float4 nc = *(const float4*)(xp + kn * 32 + 4);

        // split current x chunk into 3 bf16 limbs, MFMA B-frag layout
        FragU xh, xm, xl;
        split2packt(ra.x, ra.y, xh.u.x, xm.u.x, xl.u.x);
        split2packt(ra.z, ra.w, xh.u.y, xm.u.y, xl.u.y);
        split2packt(rc.x, rc.y, xh.u.z, xm.u.z, xl.u.z);
        split2packt(rc.z, rc.w, xh.u.w, xm.u.w, xl.u.w);

        #pragma unroll
        for (int jt = 0; jt < 9; ++jt) {
            const int pl = jt * 4 + ks;
            FragU wh, wm, wl;
            wh.u = Wl4[(0 * 36 + pl) * 64 + lane];
            wm.u = Wl4[(1 * 36 + pl) * 64 + lane];
            wl.u = Wl4[(2 * 36 + pl) * 64 + lane];
            f32x4 c = acc[jt];
            c = __builtin_amdgcn_mfma_f32_16x16x32_bf16(wl.f, xh.f, c, 0, 0, 0);
            c = __builtin_amdgcn_mfma_f32_16x16x32_bf16(wh.f, xl.f, c, 0, 0, 0);
            c = __builtin_amdgcn_mfma_f32_16x16x32_bf16(wm.f, xm.f, c, 0, 0, 0);
            c = __builtin_amdgcn_mfma_f32_16x16x32_bf16(wm.f, xh.f, c, 0, 0, 0);
            c = __builtin_amdgcn_mfma_f32_16x16x32_bf16(wh.f, xm.f, c, 0, 0, 0);
            c = __builtin_amdgcn_mfma_f32_16x16x32_bf16(wh.f, xh.f, c, 0, 0, 0);
            acc[jt] = c;
        }
        ra = na; rc = nc;
    }

    // ---- quadratic sums: s2 = sum h^2, t2 = sum g^2 h^2 ----
    float s2a = 0.f, t2a = 0.f;
    #pragma unroll
    for (int jt = 0; jt < 8; ++jt) {
        AccU a; a.v = acc[jt];
        #pragma unroll
        for (int r = 0; r < 4; ++r) {
            int j = jt * 16 + q * 4 + r;
            float2 gb = *(const float2*)&g2b_s[2 * j];
            float h = a.a[r] + gb.y;
            float h2 = h * h;
            s2a += h2;
            t2a = fmaf(gb.x, h2, t2a);
        }
    }
    s2a += __shfl_xor(s2a, 16); s2a += __shfl_xor(s2a, 32);
    t2a += __shfl_xor(t2a, 16); t2a += __shfl_xor(t2a, 32);

    // ---- all-gather 11 folded linear sums (jt==8 accs) across quads ----
    {
        AccU mine; mine.v = acc[8];
        *(float4*)&gath[wave][ml * 20 + q * 4] = *(float4*)mine.a;
    }
    __builtin_amdgcn_s_waitcnt(0);
    float4 A  = *(const float4*)&gath[wave][ml * 20 + 0];
    float4 Bv = *(const float4*)&gath[wave][ml * 20 + 4];
    float4 C  = *(const float4*)&gath[wave][ml * 20 + 8];

    const float inv128 = 1.0f / 128.0f;
    const float cg2s = scal_s[16], cgbs = scal_s[17], cb2s = scal_s[18];

    float s1  = A.x + scal_s[19];
    float t1  = A.y + scal_s[20];
    float r1v = A.z + scal_s[21];
    float u[KK] = {A.w + scal_s[22], Bv.x + scal_s[23], Bv.y + scal_s[24],
                   Bv.z + scal_s[25], Bv.w + scal_s[26], C.x + scal_s[27],
                   C.y + scal_s[28], C.z + scal_s[29]};

    float mu = s1 * inv128;
    float var = fmaf(-mu, mu, s2a * inv128);
    float istd = 1.0f / sqrtf(var + LN_EPS);
    float nrm2 = istd * istd * (t2a - 2.f * mu * t1 + mu * mu * cg2s)
               + 2.f * istd * (r1v - mu * cgbs) + cb2s;
    float rinv = 1.0f / fmaxf(sqrtf(fmaxf(nrm2, 0.f)), NORM_EPS);

    float lg[KK];
    #pragma unroll
    for (int k = 0; k < KK; ++k)
        lg[k] = (istd * (u[k] - mu * scal_s[k]) + scal_s[8 + k]) * rinv;

    float mx = lg[0]; int bi = 0;
    #pragma unroll
    for (int k = 1; k < KK; ++k) if (lg[k] > mx) { mx = lg[k]; bi = k; }

    float ex[KK], se = 0.f;
    #pragma unroll
    for (int k = 0; k < KK; ++k) { ex[k] = expf(lg[k] - mx); se += ex[k]; }
    float rse = 1.0f / se;

    const int m = rowbase + ml;
    if (q == 0) {
        out_idx[m] = (float)bi;
        *(float4*)&out_log[(size_t)m * KK + 4] = make_float4(lg[4], lg[5], lg[6], lg[7]);
        besti[wave][ml] = bi;
    } else if (q == 1) {
        *(float4*)&out_soft[(size_t)m * KK] = make_float4(ex[0] * rse, ex[1] * rse, ex[2] * rse, ex[3] * rse);
    } else if (q == 2) {
        *(float4*)&out_soft[(size_t)m * KK + 4] = make_float4(ex[4] * rse, ex[5] * rse, ex[6] * rse, ex[7] * rse);
    } else {
        *(float4*)&out_log[(size_t)m * KK] = make_float4(lg[0], lg[1], lg[2], lg[3]);
    }

    // ---- embedding: emb[row] = codebook[best[row]], coalesced per wave ----
    __builtin_amdgcn_s_waitcnt(0);
    const float4* cb4 = (const float4*)cb;
    float4* eo = (float4*)out_emb;
    #pragma unroll
    for (int i = 0; i < 8; ++i) {
        int f4 = lane + 64 * i;          // 0..511 over 16 rows x 32 float4
        int rl = f4 >> 5;
        int c  = f4 & 31;
        int k0 = besti[wave][rl];
        eo[(size_t)(rowbase + rl) * 32 + c] = cb4[k0 * 32 + c];
    }
}

extern "C" void kernel_launch(void* const* d_in, const int* in_sizes, int n_in,
                              void* d_out, int out_size, void* d_ws, size_t ws_size,
                              hipStream_t stream) {
    const float* x     = (const float*)d_in[0];
    const float* W     = (const float*)d_in[1];
    const float* b     = (const float*)d_in[2];
    const float* gamma = (const float*)d_in[3];
    const float* beta  = (const float*)d_in[4];
    const float* cb    = (const float*)d_in[5];
    const int B = in_sizes[0] / DD;

    float*  ws  = (float*)d_ws;
    ushort* wsA = (ushort*)d_ws;

    float* out    = (float*)d_out;
    float* o_idx  = out;
    float* o_soft = out + (size_t)B;
    float* o_emb  = out + (size_t)B * (1 + KK);
    float* o_log  = out + (size_t)B * (1 + KK + DD);

    hipLaunchKernelGGL(l1q_prep0, dim3(1), dim3(128), 0, stream, b, gamma, beta, cb, ws);
    hipLaunchKernelGGL(l1q_prepA, dim3(36), dim3(256), 0, stream, W, b, gamma, beta, cb, wsA);
    const int grid = B / 256;
    hipLaunchKernelGGL(l1q_main, dim3(grid), dim3(1024), 0, stream,
                       x, wsA, ws, cb, o_idx, o_soft, o_emb, o_log, B);
}

// Round 5
// 297.681 us; speedup vs baseline: 1.9870x; 1.0938x over previous
//
#include <hip/hip_runtime.h>
#include <math.h>

#define DD 128
#define KK 8
#define LN_EPS 1e-5f
#define NORM_EPS 1e-12f

typedef __attribute__((ext_vector_type(8))) short bf16x8;
typedef __attribute__((ext_vector_type(16))) float f32x16;
typedef unsigned int uint;
typedef unsigned short ushort;

// ws layout (bytes):
//   [0, 122880)        wsA: packed bf16 A-frags of W_ext (160x128):
//                      [split(3)][jt(5)][ks(8)][lane(64)][8 bf16]
//   [122880, 123904)   g2b: 128 x {gamma^2, bias} float2
//   [123904, 124032)   scal[32]: 0..7 pk, 8..15 q0k, 16 cg2s, 17 cgbs,
//                      18 cb2s, 19 cs1, 20 ct1, 21 cr1, 22..29 cuk
#define G2B_OFF_F   (122880 / 4)
#define SCAL_OFF_F  (123904 / 4)

// exact 3-way bf16 split with RNE (prep only)
__device__ inline void split3(float x, uint& h, uint& m, uint& l) {
    uint u0 = __float_as_uint(x);
    uint rh = (u0 + 0x7FFFu + ((u0 >> 16) & 1u)) & 0xFFFF0000u;
    float xh = __uint_as_float(rh);
    float r1 = x - xh;
    uint u1 = __float_as_uint(r1);
    uint rm = (u1 + 0x7FFFu + ((u1 >> 16) & 1u)) & 0xFFFF0000u;
    float xm = __uint_as_float(rm);
    float r2 = r1 - xm;
    uint u2 = __float_as_uint(r2);
    uint rl = (u2 + 0x7FFFu + ((u2 >> 16) & 1u));
    h = rh; m = rm; l = rl;
}

// cheap truncating 3-way split (main loop); residuals exact, last limb trunc.
__device__ inline void split3t(float x, uint& h, uint& m, uint& l) {
    uint u0 = __float_as_uint(x);
    float xh = __uint_as_float(u0 & 0xFFFF0000u);
    float r1 = x - xh;
    uint u1 = __float_as_uint(r1);
    float xm = __uint_as_float(u1 & 0xFFFF0000u);
    float r2 = r1 - xm;
    h = u0; m = u1; l = __float_as_uint(r2);
}

__device__ inline uint packhi(uint a1, uint a0) {
    return __builtin_amdgcn_perm(a1, a0, 0x07060302u);
}

__device__ inline void split2packt(float e0, float e1, uint& ph, uint& pm, uint& pl) {
    uint h0, m0, l0, h1, m1, l1;
    split3t(e0, h0, m0, l0);
    split3t(e1, h1, m1, l1);
    ph = packhi(h1, h0);
    pm = packhi(m1, m0);
    pl = packhi(l1, l0);
}

union FragU  { uint4 u; bf16x8 f; };
union AccU16 { f32x16 v; float a[16]; };

// ---------------------------------------------------------------------------
// prep0: scalar tables (1 block x 128 threads)
// ---------------------------------------------------------------------------
__global__ void l1q_prep0(const float* __restrict__ b, const float* __restrict__ gamma,
                          const float* __restrict__ beta, const float* __restrict__ cb,
                          float* __restrict__ ws)
{
    __shared__ float invn_s[KK];
    const int t = threadIdx.x;  // 128
    if (t < KK) {
        float s = 0.f;
        for (int j = 0; j < DD; ++j) { float v = cb[t * DD + j]; s = fmaf(v, v, s); }
        invn_s[t] = 1.0f / fmaxf(sqrtf(s), NORM_EPS);
    }
    __syncthreads();
    {
        float g = gamma[t];
        float* g2b = ws + G2B_OFF_F;
        g2b[2 * t]     = g * g;
        g2b[2 * t + 1] = b[t];
    }
    float* scal = ws + SCAL_OFF_F;
    if (t < KK) {
        float in = invn_s[t];
        float p = 0.f, q = 0.f, cu = 0.f;
        for (int j = 0; j < DD; ++j) {
            float c = cb[t * DD + j] * in;
            p  = fmaf(c, gamma[j], p);
            q  = fmaf(c, beta[j], q);
            cu = fmaf(c * gamma[j], b[j], cu);
        }
        scal[t]      = p;   // pk
        scal[8 + t]  = q;   // q0k
        scal[22 + t] = cu;  // cuk
    }
    if (t == 16) { float s = 0.f; for (int j = 0; j < DD; ++j) { float g = gamma[j]; s = fmaf(g, g, s); } scal[16] = s; }
    if (t == 17) { float s = 0.f; for (int j = 0; j < DD; ++j) s = fmaf(gamma[j], beta[j], s); scal[17] = s; }
    if (t == 18) { float s = 0.f; for (int j = 0; j < DD; ++j) { float v = beta[j]; s = fmaf(v, v, s); } scal[18] = s; }
    if (t == 19) { float s = 0.f; for (int j = 0; j < DD; ++j) s += b[j]; scal[19] = s; }                        // cs1
    if (t == 20) { float s = 0.f; for (int j = 0; j < DD; ++j) s = fmaf(gamma[j] * gamma[j], b[j], s); scal[20] = s; } // ct1
    if (t == 21) { float s = 0.f; for (int j = 0; j < DD; ++j) s = fmaf(gamma[j] * beta[j], b[j], s); scal[21] = s; }  // cr1
}

// ---------------------------------------------------------------------------
// prepA: build W_ext (160x128: 128 W rows + 11 folded + 21 zero), 3-way split,
// pack into 32x32x16 MFMA A-frag layout. grid 40 blocks: bid -> (jt, ks).
// A-frag: lane = m_local + 32*(k_local>>3), elem i = k_local&7.
// ---------------------------------------------------------------------------
__global__ void l1q_prepA(const float* __restrict__ W, const float* __restrict__ b,
                          const float* __restrict__ gamma, const float* __restrict__ beta,
                          const float* __restrict__ cb, ushort* __restrict__ wsA)
{
    __shared__ float invn_s[KK];
    __shared__ float we[11][DD];
    __shared__ float wext[32][16];
    const int t = threadIdx.x;          // 256
    const int jt = blockIdx.x >> 3;     // 0..4
    const int ks = blockIdx.x & 7;      // 0..7

    if (jt == 4) {
        if (t < KK) {
            float s = 0.f;
            for (int j = 0; j < DD; ++j) { float v = cb[t * DD + j]; s = fmaf(v, v, s); }
            invn_s[t] = 1.0f / fmaxf(sqrtf(s), NORM_EPS);
        }
        __syncthreads();
        for (int idx = t; idx < 11 * DD; idx += 256) {
            int e = idx / DD, j = idx % DD;
            float g = gamma[j];
            float v;
            if (e == 0)      v = 1.0f;
            else if (e == 1) v = g * g;
            else if (e == 2) v = g * beta[j];
            else             v = cb[(e - 3) * DD + j] * invn_s[e - 3] * g;
            we[e][j] = v;
        }
        __syncthreads();
    }

    for (int idx = t; idx < 512; idx += 256) {
        int jl = idx >> 4, kk = idx & 15;
        int k = ks * 16 + kk;
        float val;
        if (jt < 4) {
            val = W[(jt * 32 + jl) * DD + k];
        } else if (jl < 11) {
            float s = 0.f;
            for (int j = 0; j < DD; ++j) s = fmaf(we[jl][j], W[j * DD + k], s);
            val = s;
        } else {
            val = 0.f;
        }
        wext[jl][kk] = val;
    }
    __syncthreads();

    for (int idx = t; idx < 512; idx += 256) {
        int jl = idx >> 4, kk = idx & 15;
        int lane = jl + 32 * (kk >> 3);
        int i = kk & 7;
        uint h, m, l;
        split3(wext[jl][kk], h, m, l);
        int base = jt * 8 + ks;
        wsA[(0 * 40 + base) * 512 + lane * 8 + i] = (ushort)(h >> 16);
        wsA[(1 * 40 + base) * 512 + lane * 8 + i] = (ushort)(m >> 16);
        wsA[(2 * 40 + base) * 512 + lane * 8 + i] = (ushort)(l >> 16);
    }
}

// ---------------------------------------------------------------------------
// main: 1024 threads = 16 waves, 32 rows/wave, 512 rows/block.
// D[j_ext][n] = W_ext x x^T via 6-product split-bf16 mfma_32x32x16.
// Lane: n = lane&31 (x-row), h = lane>>5 (k-half). C/D row = (reg&3)+8*(reg>>2)+4*h.
// ---------------------------------------------------------------------------
__global__ __launch_bounds__(1024, 4)
void l1q_main(const float* __restrict__ x, const ushort* __restrict__ wsA,
              const float* __restrict__ wsf, const float* __restrict__ cb,
              float* __restrict__ out_idx, float* __restrict__ out_soft,
              float* __restrict__ out_emb, float* __restrict__ out_log,
              int B)
{
    __shared__ uint4 Wl4[7680];        // 122880 B packed W_ext frags
    __shared__ float gath[16][352];    // [wave][n*11 + local], gcd(11,32)=1
    __shared__ int   besti[16][32];
    __shared__ float g2b_s[256];
    __shared__ float scal_s[32];

    const int t = threadIdx.x;
    const int wave = t >> 6;
    const int lane = t & 63;
    const int n = lane & 31;
    const int h = lane >> 5;
    const int rowbase = blockIdx.x * 512 + wave * 32;
    const int row = rowbase + n;

    const float* xp = x + (size_t)row * DD + h * 8;
    float4 ra = *(const float4*)(xp + 0);    // ks=0 chunk, issued early
    float4 rc = *(const float4*)(xp + 4);

    {
        const uint4* src = (const uint4*)wsA;
        #pragma unroll
        for (int i = 0; i < 8; ++i) {
            int idx = t + i * 1024;
            if (idx < 7680) Wl4[idx] = src[idx];
        }
    }
    if (t < 256) g2b_s[t] = wsf[G2B_OFF_F + t];
    if (t < 32)  scal_s[t] = wsf[SCAL_OFF_F + t];
    __syncthreads();

    f32x16 acc[5];
    #pragma unroll
    for (int jt = 0; jt < 5; ++jt)
        #pragma unroll
        for (int r = 0; r < 16; ++r) acc[jt][r] = 0.f;

    #pragma unroll
    for (int ks = 0; ks < 8; ++ks) {
        int kn = ks < 7 ? ks + 1 : 7;
        float4 na = *(const float4*)(xp + kn * 16 + 0);
        float4 nc = *(const float4*)(xp + kn * 16 + 4);

        FragU xh, xm, xl;
        split2packt(ra.x, ra.y, xh.u.x, xm.u.x, xl.u.x);
        split2packt(ra.z, ra.w, xh.u.y, xm.u.y, xl.u.y);
        split2packt(rc.x, rc.y, xh.u.z, xm.u.z, xl.u.z);
        split2packt(rc.z, rc.w, xh.u.w, xm.u.w, xl.u.w);

        #pragma unroll
        for (int jt = 0; jt < 5; ++jt) {
            const int pl = jt * 8 + ks;
            FragU wh, wm, wl;
            wh.u = Wl4[(0 * 40 + pl) * 64 + lane];
            wm.u = Wl4[(1 * 40 + pl) * 64 + lane];
            wl.u = Wl4[(2 * 40 + pl) * 64 + lane];
            f32x16 c = acc[jt];
            c = __builtin_amdgcn_mfma_f32_32x32x16_bf16(wl.f, xh.f, c, 0, 0, 0);
            c = __builtin_amdgcn_mfma_f32_32x32x16_bf16(wh.f, xl.f, c, 0, 0, 0);
            c = __builtin_amdgcn_mfma_f32_32x32x16_bf16(wm.f, xm.f, c, 0, 0, 0);
            c = __builtin_amdgcn_mfma_f32_32x32x16_bf16(wm.f, xh.f, c, 0, 0, 0);
            c = __builtin_amdgcn_mfma_f32_32x32x16_bf16(wh.f, xm.f, c, 0, 0, 0);
            c = __builtin_amdgcn_mfma_f32_32x32x16_bf16(wh.f, xh.f, c, 0, 0, 0);
            acc[jt] = c;
        }
        ra = na; rc = nc;
    }

    // ---- quadratic sums over true W rows (jt 0..3) ----
    float s2a = 0.f, t2a = 0.f;
    #pragma unroll
    for (int jt = 0; jt < 4; ++jt) {
        AccU16 a; a.v = acc[jt];
        #pragma unroll
        for (int rq = 0; rq < 4; ++rq) {
            int jb = jt * 32 + 8 * rq + 4 * h;
            #pragma unroll
            for (int r = 0; r < 4; ++r) {
                float2 gb = *(const float2*)&g2b_s[2 * (jb + r)];
                float hv = a.a[rq * 4 + r] + gb.y;
                float h2 = hv * hv;
                s2a += h2;
                t2a = fmaf(gb.x, h2, t2a);
            }
        }
    }
    s2a += __shfl_xor(s2a, 32);
    t2a += __shfl_xor(t2a, 32);

    // ---- gather 11 folded linear sums (tile jt=4, locals 0..10) ----
    {
        AccU16 a; a.v = acc[4];
        #pragma unroll
        for (int rq = 0; rq < 4; ++rq) {
            #pragma unroll
            for (int r = 0; r < 4; ++r) {
                int local = r + 8 * rq + 4 * h;
                if (local < 11) gath[wave][n * 11 + local] = a.a[rq * 4 + r];
            }
        }
    }
    __builtin_amdgcn_s_waitcnt(0);   // wave-internal LDS ordering
    const float* gp = &gath[wave][n * 11];

    const float inv128 = 1.0f / 128.0f;
    const float cg2s = scal_s[16], cgbs = scal_s[17], cb2s = scal_s[18];

    float s1  = gp[0] + scal_s[19];
    float t1  = gp[1] + scal_s[20];
    float r1v = gp[2] + scal_s[21];
    float u[KK];
    #pragma unroll
    for (int k = 0; k < KK; ++k) u[k] = gp[3 + k] + scal_s[22 + k];

    float mu = s1 * inv128;
    float var = fmaf(-mu, mu, s2a * inv128);
    float istd = 1.0f / sqrtf(var + LN_EPS);
    float nrm2 = istd * istd * (t2a - 2.f * mu * t1 + mu * mu * cg2s)
               + 2.f * istd * (r1v - mu * cgbs) + cb2s;
    float rinv = 1.0f / fmaxf(sqrtf(fmaxf(nrm2, 0.f)), NORM_EPS);

    float lg[KK];
    #pragma unroll
    for (int k = 0; k < KK; ++k)
        lg[k] = (istd * (u[k] - mu * scal_s[k]) + scal_s[8 + k]) * rinv;

    float mx = lg[0]; int bi = 0;
    #pragma unroll
    for (int k = 1; k < KK; ++k) if (lg[k] > mx) { mx = lg[k]; bi = k; }

    float ex[KK], se = 0.f;
    #pragma unroll
    for (int k = 0; k < KK; ++k) { ex[k] = expf(lg[k] - mx); se += ex[k]; }
    float rse = 1.0f / se;

    const int m = rowbase + n;
    if (h == 0) {
        out_idx[m] = (float)bi;
        besti[wave][n] = bi;
        *(float4*)&out_log[(size_t)m * KK]     = make_float4(lg[0], lg[1], lg[2], lg[3]);
        *(float4*)&out_log[(size_t)m * KK + 4] = make_float4(lg[4], lg[5], lg[6], lg[7]);
    } else {
        *(float4*)&out_soft[(size_t)m * KK]     = make_float4(ex[0] * rse, ex[1] * rse, ex[2] * rse, ex[3] * rse);
        *(float4*)&out_soft[(size_t)m * KK + 4] = make_float4(ex[4] * rse, ex[5] * rse, ex[6] * rse, ex[7] * rse);
    }

    // ---- embedding: emb[row] = codebook[best[row]], coalesced per wave ----
    __builtin_amdgcn_s_waitcnt(0);
    const float4* cb4 = (const float4*)cb;
    float4* eo = (float4*)out_emb;
    #pragma unroll
    for (int i = 0; i < 16; ++i) {
        int f4 = lane + 64 * i;          // 0..1023 over 32 rows x 32 float4
        int rl = f4 >> 5;
        int c  = f4 & 31;
        int k0 = besti[wave][rl];
        eo[(size_t)(rowbase + rl) * 32 + c] = cb4[k0 * 32 + c];
    }
}

extern "C" void kernel_launch(void* const* d_in, const int* in_sizes, int n_in,
                              void* d_out, int out_size, void* d_ws, size_t ws_size,
                              hipStream_t stream) {
    const float* x     = (const float*)d_in[0];
    const float* W     = (const float*)d_in[1];
    const float* b     = (const float*)d_in[2];
    const float* gamma = (const float*)d_in[3];
    const float* beta  = (const float*)d_in[4];
    const float* cb    = (const float*)d_in[5];
    const int B = in_sizes[0] / DD;

    float*  ws  = (float*)d_ws;
    ushort* wsA = (ushort*)d_ws;

    float* out    = (float*)d_out;
    float* o_idx  = out;
    float* o_soft = out + (size_t)B;
    float* o_emb  = out + (size_t)B * (1 + KK);
    float* o_log  = out + (size_t)B * (1 + KK + DD);

    hipLaunchKernelGGL(l1q_prep0, dim3(1), dim3(128), 0, stream, b, gamma, beta, cb, ws);
    hipLaunchKernelGGL(l1q_prepA, dim3(40), dim3(256), 0, stream, W, b, gamma, beta, cb, wsA);
    const int grid = B / 512;
    hipLaunchKernelGGL(l1q_main, dim3(grid), dim3(1024), 0, stream,
                       x, wsA, ws, cb, o_idx, o_soft, o_emb, o_log, B);
}